// Round 1
// baseline (248.811 us; speedup 1.0000x reference)
//
#include <hip/hip_runtime.h>

// ---------------------------------------------------------------------------
// TemporalHyperedge: loss[b] = 0.2 * sum_n ||cur[b]@r_proj - W@pre[b]||_2
//                              + sum_n (max_m W[n,m] + 0.001*||W[n,:]||_2)
// W = incidence_m masked to > 0.01. Output = [loss(32) , incidence_m(2048^2)].
//
// R5 change: gemm_diff rewritten as a 256x256-tile, 8-wave, 8-phase pipelined
// kernel (T3+T4+T5 from the CDNA4 catalog). 2 K-tile LDS double buffer
// (132 KB), phases = (qa half-of-A-rows, k-half) quadrants, each phase issues
// 0-2 half-tile global_load_lds stages into regions freed >=1 barrier earlier;
// counted s_waitcnt vmcnt(2) at phases 4/8 only (no vmcnt(0) drain in the main
// loop), raw asm s_barrier (compiler memory fence), s_setprio around MFMA.
// cur(f32)@rprojT tail (tiles 32..35) stays a simple 2-barrier loop.
// prep_all / finalize unchanged from R4.
// ---------------------------------------------------------------------------

typedef __attribute__((ext_vector_type(8))) short bf16x8;
typedef __attribute__((ext_vector_type(8))) unsigned short ushort8;
typedef __attribute__((ext_vector_type(16))) float f32x16;

__device__ __forceinline__ unsigned short f2bf(float f) {
    union { float f; unsigned u; } x; x.f = f;
    unsigned r = x.u + 0x7fffu + ((x.u >> 16) & 1u);   // RNE
    return (unsigned short)(r >> 16);
}

#define GLL16(g, l)                                                         \
    __builtin_amdgcn_global_load_lds(                                       \
        (const __attribute__((address_space(1))) void*)(g),                 \
        (__attribute__((address_space(3))) void*)(l), 16, 0, 0)

// --------------------------------------------------------------------------
// transpose_64x64: src f32 (R,C) tile (r0,c0) -> dst bf16 (C,R).
// --------------------------------------------------------------------------
__device__ __forceinline__ void transpose_64x64(
    const float* __restrict__ src, unsigned short* __restrict__ dst,
    int R, int C, int r0, int c0, unsigned short* __restrict__ tile) {
    const int t = threadIdx.x;
    const int fr = t >> 4, fc = (t & 15) * 4;
#pragma unroll
    for (int it = 0; it < 4; ++it) {
        int m = fr + it * 16;
        float4 v = *(const float4*)(src + (size_t)(r0 + m) * C + c0 + fc);
        tile[(fc + 0) * 68 + m] = f2bf(v.x);
        tile[(fc + 1) * 68 + m] = f2bf(v.y);
        tile[(fc + 2) * 68 + m] = f2bf(v.z);
        tile[(fc + 3) * 68 + m] = f2bf(v.w);
    }
    __syncthreads();
    const int d = t >> 2, m0 = (t & 3) * 16;
    unsigned short v[16];
#pragma unroll
    for (int j = 0; j < 4; ++j)
        *(ushort4*)(v + j * 4) = *(const ushort4*)(tile + d * 68 + m0 + j * 4);
    unsigned short* dp = dst + (size_t)(c0 + d) * R + r0 + m0;
    ushort8 p0, p1;
#pragma unroll
    for (int j = 0; j < 8; ++j) { p0[j] = v[j]; p1[j] = v[8 + j]; }
    *(ushort8*)(dp) = p0;
    *(ushort8*)(dp + 8) = p1;
}

// --------------------------------------------------------------------------
// prep_all — block sections:
//   [0,2048)    : incidence row: copy-out, -masked bf16 W, crow[row]=l1+1e-3*l2
//   [2048,6144) : pre (32,2048,256) -> preT (32,256,2048) bf16 transpose
//   [6144,6160) : r_proj (256,256) -> rprojT bf16 transpose
// --------------------------------------------------------------------------
__global__ __launch_bounds__(256) void prep_all(
    const float* __restrict__ inc, float* __restrict__ out_inc,
    unsigned short* __restrict__ Wneg, float* __restrict__ crow,
    const float* __restrict__ pre, unsigned short* __restrict__ preT,
    const float* __restrict__ r_proj, unsigned short* __restrict__ rprojT) {
    __shared__ unsigned short tile[64 * 68];
    __shared__ float smax[4], ssum[4];
    const int bid = blockIdx.x;
    const int t = threadIdx.x;

    if (bid < 2048) {
        const int row = bid;
        const float4* src = (const float4*)(inc + (size_t)row * 2048);
        float4* dst = (float4*)(out_inc + (size_t)row * 2048);
        ushort4* wp = (ushort4*)(Wneg + (size_t)row * 2048);
        float lmax = 0.f, ss = 0.f;
#pragma unroll
        for (int it = 0; it < 2; ++it) {
            int i = it * 256 + t;
            float4 v = src[i];
            dst[i] = v;
            float w0 = v.x > 0.01f ? v.x : 0.f;
            float w1 = v.y > 0.01f ? v.y : 0.f;
            float w2 = v.z > 0.01f ? v.z : 0.f;
            float w3 = v.w > 0.01f ? v.w : 0.f;
            ushort4 p;
            p.x = f2bf(-w0); p.y = f2bf(-w1); p.z = f2bf(-w2); p.w = f2bf(-w3);
            wp[i] = p;
            lmax = fmaxf(lmax, fmaxf(fmaxf(w0, w1), fmaxf(w2, w3)));
            ss += w0 * w0 + w1 * w1 + w2 * w2 + w3 * w3;
        }
#pragma unroll
        for (int off = 32; off; off >>= 1) {
            lmax = fmaxf(lmax, __shfl_down(lmax, off));
            ss += __shfl_down(ss, off);
        }
        int wv = t >> 6, ln = t & 63;
        if (ln == 0) { smax[wv] = lmax; ssum[wv] = ss; }
        __syncthreads();
        if (t == 0) {
            float m = fmaxf(fmaxf(smax[0], smax[1]), fmaxf(smax[2], smax[3]));
            float s = ssum[0] + ssum[1] + ssum[2] + ssum[3];
            crow[row] = m + 0.001f * sqrtf(s);
        }
    } else if (bid < 6144) {
        const int tt = bid - 2048;
        const int b = tt >> 7;
        const int mt = (tt & 127) >> 2;
        const int dt = tt & 3;
        transpose_64x64(pre + (size_t)b * 524288, preT + (size_t)b * 524288,
                        2048, 256, mt * 64, dt * 64, tile);
    } else {
        const int tt = bid - 6144;
        transpose_64x64(r_proj, rprojT, 256, 256, (tt >> 2) * 64, (tt & 3) * 64,
                        tile);
    }
}

// --------------------------------------------------------------------------
// gemm_diff: block = 256n x 256d, BK=64, K=2304. 32x32x16 MFMA, 8 waves 2x4,
// per-wave C = 128x64 (acc[4][2] f32x16). LDS: 2 K-tile double buffer,
// chunk-swizzled (LDS[r][p] = G[r][p ^ (r&7)], p = 16B chunk idx).
//
// 8-phase schedule per iteration (2 K-tiles: buf0 = tile 2j, buf1 = 2j+1):
//   ph1 (b0,qa0,kh0): stage b1.Aqa1, b1.Bu0 (tile 2j+1)
//   ph2 (b0,qa1,kh0): stage b1.Bu1
//   ph3 (b0,qa0,kh1): -
//   ph4 (b0,qa1,kh1): stage b0.Aqa0 (tile 2j+2)    + vmcnt(2)
//   ph5 (b1,qa0,kh0): stage b0.Aqa1, b0.Bu0
//   ph6 (b1,qa1,kh0): stage b0.Bu1
//   ph7 (b1,qa0,kh1): -
//   ph8 (b1,qa1,kh1): stage b1.Aqa0 (tile 2j+3)    + vmcnt(2)
// Every staged unit: region freed >=1 barrier before issue (WAR), and >=3
// phases + a vmcnt(2) before first read (RAW). Last main iter drains at ph4.
// --------------------------------------------------------------------------
__global__ __launch_bounds__(512, 2) void gemm_diff(
    const unsigned short* __restrict__ Wneg,    // (2048,2048) bf16 neg+masked
    const float* __restrict__ cur,              // (32,2048,256) f32
    const unsigned short* __restrict__ preT,    // (32,256,2048) bf16
    const unsigned short* __restrict__ rprojT,  // (256,256) bf16
    float* __restrict__ Ssq)                    // (32,2048)
{
    const int n0 = blockIdx.x * 256;
    const int b  = blockIdx.y;

    __shared__ unsigned short Al[2][256 * 64];  // 64 KB
    __shared__ unsigned short Bl[2][256 * 64];  // 64 KB
    __shared__ float ssq[256];

    const int tid   = threadIdx.x;
    const int w     = tid >> 6;
    const int lane  = tid & 63;
    const int l32   = lane & 31;
    const int half  = lane >> 5;
    const int wm128 = (w >> 2) * 128;
    const int wn64  = (w & 3) * 64;
    const int w8    = w * 8;
    const int grow  = lane >> 3;                 // row-within-8 for staging
    const int gbyte = ((lane & 7) ^ grow) * 16;  // swizzled source chunk
    const int sw    = (l32 & 7) * 8;             // fragment-read swizzle base

    if (tid < 256) ssq[tid] = 0.f;

    f32x16 acc[4][2] = {};

    const float*          curB = cur  + (size_t)b * 2048 * 256;
    const unsigned short* preB = preT + (size_t)b * 256 * 2048;
    const unsigned short* An   = Wneg + (size_t)n0 * 2048;

    // stage one A unit (qa): rows {qa*64+i} u {128+qa*64+i}, 2 GLL passes
#define STAGE_A(AP, qa, K0)                                                    \
    {                                                                          \
        _Pragma("unroll") for (int pass = 0; pass < 2; ++pass) {               \
            const int rowb = (qa) * 64 + pass * 128 + w8;                      \
            GLL16((const char*)(An + (size_t)(rowb + grow) * 2048 + (K0)) + gbyte, \
                  (char*)(AP) + rowb * 128);                                   \
        }                                                                      \
    }
    // stage one B unit (u): rows u*128 .. u*128+127, 2 GLL passes
#define STAGE_B(BP, u, K0)                                                     \
    {                                                                          \
        _Pragma("unroll") for (int pass = 0; pass < 2; ++pass) {               \
            const int rowb = (u) * 128 + pass * 64 + w8;                       \
            GLL16((const char*)(preB + (size_t)(rowb + grow) * 2048 + (K0)) + gbyte, \
                  (char*)(BP) + rowb * 128);                                   \
        }                                                                      \
    }

    // ---- prologue: tile0 -> buf0 (Aqa0, Bu0, Bu1, Aqa1), tile1 -> buf1.Aqa0
    STAGE_A(Al[0], 0, 0);
    STAGE_B(Bl[0], 0, 0);
    STAGE_B(Bl[0], 1, 0);
    STAGE_A(Al[0], 1, 0);
    STAGE_A(Al[1], 0, 64);
    asm volatile("s_waitcnt vmcnt(2)" ::: "memory");  // buf0 landed; b1.Aqa0 flies
    asm volatile("s_barrier" ::: "memory");

    bf16x8 bfr[2][2];  // B frags for current k-half, reused across qa0/qa1

#define LOADB(BP, kh)                                                          \
    _Pragma("unroll") for (int ni = 0; ni < 2; ++ni)                           \
    _Pragma("unroll") for (int ksl = 0; ksl < 2; ++ksl)                        \
        bfr[ni][ksl] = *(const bf16x8*)((BP) + (wn64 + ni * 32 + l32) * 64 +   \
                           (((((kh) * 2 + ksl) * 2 + half) * 8) ^ sw));

#define PHASE(AP, qa, kh, STAGES, VMW)                                         \
    {                                                                          \
        bf16x8 af[2][2];                                                       \
        _Pragma("unroll") for (int mi = 0; mi < 2; ++mi)                       \
        _Pragma("unroll") for (int ksl = 0; ksl < 2; ++ksl)                    \
            af[mi][ksl] = *(const bf16x8*)((AP) +                              \
                (wm128 + (qa) * 64 + mi * 32 + l32) * 64 +                     \
                (((((kh) * 2 + ksl) * 2 + half) * 8) ^ sw));                   \
        STAGES                                                                 \
        VMW                                                                    \
        asm volatile("s_barrier" ::: "memory");                                \
        __builtin_amdgcn_s_setprio(1);                                         \
        _Pragma("unroll") for (int mi = 0; mi < 2; ++mi)                       \
        _Pragma("unroll") for (int ni = 0; ni < 2; ++ni)                       \
        _Pragma("unroll") for (int ksl = 0; ksl < 2; ++ksl)                    \
            acc[(qa) * 2 + mi][ni] = __builtin_amdgcn_mfma_f32_32x32x16_bf16(  \
                af[mi][ksl], bfr[ni][ksl], acc[(qa) * 2 + mi][ni], 0, 0, 0);   \
        __builtin_amdgcn_s_setprio(0);                                         \
        asm volatile("s_barrier" ::: "memory");                                \
    }

    for (int j = 0; j < 16; ++j) {
        const int k1 = (2 * j + 1) * 64;
        const int k2 = (2 * j + 2) * 64;
        const int k3 = (2 * j + 3) * 64;
        const bool s2 = (2 * j + 2) < 32;
        const bool s3 = (2 * j + 3) < 32;

        LOADB(Bl[0], 0);
        PHASE(Al[0], 0, 0, { STAGE_A(Al[1], 1, k1); STAGE_B(Bl[1], 0, k1); }, {})
        PHASE(Al[0], 1, 0, { STAGE_B(Bl[1], 1, k1); }, {})
        LOADB(Bl[0], 1);
        PHASE(Al[0], 0, 1, {}, {})
        PHASE(Al[0], 1, 1, { if (s2) STAGE_A(Al[0], 0, k2); },
              { if (j == 15) { asm volatile("s_waitcnt vmcnt(0)" ::: "memory"); }
                else         { asm volatile("s_waitcnt vmcnt(2)" ::: "memory"); } })
        LOADB(Bl[1], 0);
        PHASE(Al[1], 0, 0, { if (s2) { STAGE_A(Al[0], 1, k2); STAGE_B(Bl[0], 0, k2); } }, {})
        PHASE(Al[1], 1, 0, { if (s2) STAGE_B(Bl[0], 1, k2); }, {})
        LOADB(Bl[1], 1);
        PHASE(Al[1], 0, 1, {}, {})
        PHASE(Al[1], 1, 1, { if (s3) STAGE_A(Al[1], 0, k3); },
              { if (j < 15) { asm volatile("s_waitcnt vmcnt(2)" ::: "memory"); } })
    }

    // ---- tail: tiles 32..35, A from cur f32 (convert + swizzled ds_write),
    //      B from rprojT via GLL. Simple 2-barrier loop, buf0 only.
    for (int kt = 32; kt < 36; ++kt) {
        __syncthreads();
        const int kk = (kt - 32) * 64;
        const int r16 = tid >> 4, k4 = tid & 15;
#pragma unroll
        for (int i = 0; i < 8; ++i) {
            const int row = r16 + i * 32;
            float4 v = *(const float4*)(curB + (size_t)(n0 + row) * 256 + kk + k4 * 4);
            ushort4 p;
            p.x = f2bf(v.x); p.y = f2bf(v.y); p.z = f2bf(v.z); p.w = f2bf(v.w);
            const int pos = ((k4 >> 1) ^ (row & 7)) * 8 + (k4 & 1) * 4;
            *(ushort4*)(&Al[0][row * 64 + pos]) = p;
        }
#pragma unroll
        for (int pass = 0; pass < 4; ++pass) {
            const int rowb = pass * 64 + w8;
            GLL16((const char*)(rprojT + (size_t)(rowb + grow) * 256 + kk) + gbyte,
                  (char*)&Bl[0][0] + rowb * 128);
        }
        __syncthreads();
#pragma unroll
        for (int ks = 0; ks < 4; ++ks) {
            const int ck = (ks * 2 + half) * 8;
#pragma unroll
            for (int mi = 0; mi < 4; ++mi) {
                bf16x8 af = *(const bf16x8*)(&Al[0][(wm128 + mi * 32 + l32) * 64 + (ck ^ sw)]);
#pragma unroll
                for (int ni = 0; ni < 2; ++ni) {
                    bf16x8 bv = *(const bf16x8*)(&Bl[0][(wn64 + ni * 32 + l32) * 64 + (ck ^ sw)]);
                    acc[mi][ni] = __builtin_amdgcn_mfma_f32_32x32x16_bf16(
                        af, bv, acc[mi][ni], 0, 0, 0);
                }
            }
        }
    }
    __syncthreads();

    // 32x32 C/D layout: col(d)=lane&31, row(n)=(reg&3)+8*(reg>>2)+4*half
#pragma unroll
    for (int mi = 0; mi < 4; ++mi)
#pragma unroll
        for (int reg = 0; reg < 16; ++reg) {
            float s = 0.f;
#pragma unroll
            for (int ni = 0; ni < 2; ++ni) {
                float v = acc[mi][ni][reg];
                s += v * v;
            }
            s += __shfl_xor(s, 1);
            s += __shfl_xor(s, 2);
            s += __shfl_xor(s, 4);
            s += __shfl_xor(s, 8);
            s += __shfl_xor(s, 16);
            if (l32 == 0) {
                const int row = (reg & 3) + 8 * (reg >> 2) + 4 * half;
                atomicAdd(&ssq[wm128 + mi * 32 + row], s);  // 4-way (wn)
            }
        }
    __syncthreads();
    if (tid < 256)
        Ssq[(size_t)b * 2048 + n0 + tid] = sqrtf(ssq[tid]);
}

// --------------------------------------------------------------------------
// finalize: loss[b] = 0.2 * sum_n Ssq[b,n] + sum_n crow[n]
// --------------------------------------------------------------------------
__global__ void finalize(const float* __restrict__ Ssq,
                         const float* __restrict__ crow,
                         float* __restrict__ out) {
    const int b = blockIdx.x;
    float s1 = 0.f, s2 = 0.f;
    for (int i = threadIdx.x; i < 2048; i += 256) {
        s1 += Ssq[(size_t)b * 2048 + i];
        s2 += crow[i];
    }
#pragma unroll
    for (int off = 32; off; off >>= 1) {
        s1 += __shfl_down(s1, off);
        s2 += __shfl_down(s2, off);
    }
    __shared__ float sm1[4], sm2[4];
    int wv = threadIdx.x >> 6, ln = threadIdx.x & 63;
    if (ln == 0) { sm1[wv] = s1; sm2[wv] = s2; }
    __syncthreads();
    if (threadIdx.x == 0)
        out[b] = 0.2f * (sm1[0] + sm1[1] + sm1[2] + sm1[3])
               + (sm2[0] + sm2[1] + sm2[2] + sm2[3]);
}

// --------------------------------------------------------------------------
extern "C" void kernel_launch(void* const* d_in, const int* in_sizes, int n_in,
                              void* d_out, int out_size, void* d_ws, size_t ws_size,
                              hipStream_t stream) {
    const float* cur    = (const float*)d_in[0];  // (32,2048,256)
    const float* pre    = (const float*)d_in[1];  // (32,2048,256)
    const float* r_proj = (const float*)d_in[2];  // (256,256)
    const float* inc    = (const float*)d_in[3];  // (2048,2048)
    float* out = (float*)d_out;                   // [0..31]=loss, [32..]=incidence

    char* ws = (char*)d_ws;
    unsigned short* Wneg   = (unsigned short*)(ws + 0);          //  8 MB
    unsigned short* preT   = (unsigned short*)(ws + 8388608);    // 32 MB
    unsigned short* rprojT = (unsigned short*)(ws + 41943040);   // 128 KB
    float*          Sbuf   = (float*)(ws + 42074112);            // 256 KB
    float*          crow   = (float*)(ws + 42336256);            // 8 KB

    prep_all<<<6160, 256, 0, stream>>>(inc, out + 32, Wneg, crow,
                                       pre, preT, r_proj, rprojT);
    gemm_diff<<<dim3(8, 32), 512, 0, stream>>>(Wneg, cur, preT, rprojT, Sbuf);
    finalize<<<32, 256, 0, stream>>>(Sbuf, crow, out);
}